// Round 13
// baseline (415.863 us; speedup 1.0000x reference)
//
#include <hip/hip_runtime.h>
#include <hip/hip_bf16.h>

#define NN 100000
#define NE 1600000
#define NG 64
#define DHID 128
#define PB 32       // blocks per graph segment in pooling stage 1
#define NBUCK 196   // dst buckets of 512 nodes (196*512 >= 100000)
#define CAPE 10240  // edge capacity per bucket (mean 8192, sigma ~90)
#define CHUNK 8192  // edges per binning workgroup

#if __has_builtin(__builtin_amdgcn_cvt_pk_f32_fp8) && __has_builtin(__builtin_amdgcn_cvt_pk_fp8_f32)
#define FP8_HW 1
#endif

typedef float f32x2 __attribute__((ext_vector_type(2)));
typedef float f32x4 __attribute__((ext_vector_type(4)));
typedef short bf16x8 __attribute__((ext_vector_type(8)));

// storage byte b <-> original column perm(b); perm(r*8+ct) = ct*16+r
#define PERM(b) ((((b) & 7) << 4) | ((b) >> 3))

// ---- fp8 e4m3fn software fallbacks (exact decode; RNE encode) ----
__device__ __forceinline__ float fp8_dec_sw(unsigned b) {
    unsigned u = ((b & 0x80u) << 24) | ((b & 0x7fu) << 20);
    return __uint_as_float(u) * 0x1p+120f;
}
__device__ __forceinline__ unsigned fp8_enc_sw(float f) {
    unsigned s = (__float_as_uint(f) >> 24) & 0x80u;
    float af = fabsf(f);
    if (!(af > 0x1p-10f)) return s;
    if (af > 448.f) af = 448.f;
    int e; float m = frexpf(af, &e);      // af = m*2^e, m in [0.5,1)
    int ee = e + 6;
    unsigned bits;
    if (ee <= 0) {
        int k = (int)rintf(af * 512.0f);
        if (k > 7) k = 7;
        bits = (unsigned)k;
    } else {
        int mm = (int)rintf(m * 16.0f);   // in [8,16]
        if (mm == 16) { mm = 8; ee += 1; }
        if (ee > 15) { ee = 15; mm = 14; }
        bits = ((unsigned)ee << 3) | (unsigned)(mm - 8);
    }
    return s | bits;
}

__device__ __forceinline__ unsigned short fp8_pack2(float a, float b) {
#ifdef FP8_HW
    return (unsigned short)__builtin_amdgcn_cvt_pk_fp8_f32(a, b, 0, false);
#else
    return (unsigned short)(fp8_enc_sw(a) | (fp8_enc_sw(b) << 8));
#endif
}

// accumulate 4 fp8 (one dword) into a0..a3
__device__ __forceinline__ void fp8_acc4(unsigned u, float& a0, float& a1, float& a2, float& a3) {
#ifdef FP8_HW
    f32x2 lo = __builtin_amdgcn_cvt_pk_f32_fp8((int)u, false);
    f32x2 hi = __builtin_amdgcn_cvt_pk_f32_fp8((int)u, true);
    a0 += lo[0]; a1 += lo[1]; a2 += hi[0]; a3 += hi[1];
#else
    a0 += fp8_dec_sw(u & 0xffu);
    a1 += fp8_dec_sw((u >> 8) & 0xffu);
    a2 += fp8_dec_sw((u >> 16) & 0xffu);
    a3 += fp8_dec_sw(u >> 24);
#endif
}

// f32 -> bf16 bits (RNE), scalar fallback path
__device__ __forceinline__ unsigned short f2bf(float f) {
    unsigned u = __float_as_uint(f);
    return (unsigned short)((u + 0x7FFFu + ((u >> 16) & 1u)) >> 16);
}

// packed f32x2 -> bf16x2 (low = a), single HW instruction on gfx950
__device__ __forceinline__ unsigned cvt_pk_bf16(float a, float b) {
#if defined(__AMDGCN__)
    unsigned r;
    asm("v_cvt_pk_bf16_f32 %0, %1, %2" : "=v"(r) : "v"(a), "v"(b));
    return r;
#else
    return (unsigned)f2bf(a) | ((unsigned)f2bf(b) << 16);
#endif
}

// ---------------- CSR build: two-level LDS-staged counting sort, both graphs ----------------

__global__ void initcur_kernel(int* __restrict__ cursor) {
    int i = blockIdx.x * 256 + threadIdx.x;
    if (i < 2 * NBUCK) cursor[i] = i * CAPE;
}

__global__ __launch_bounds__(256) void bin_kernel(const int* __restrict__ ei0, const int* __restrict__ ei1,
                                                  int* __restrict__ cursor,
                                                  unsigned int* __restrict__ binned, int E, int nch) {
    __shared__ int hist[256], scn[256], lofs[256], lcur[256], basex[256];
    __shared__ unsigned int stage[CHUNK];
    __shared__ unsigned char stageB[CHUNK];
    int g = blockIdx.x / nch;
    int ch = blockIdx.x - g * nch;
    const int* ei = g ? ei1 : ei0;
    int* cur = cursor + g * NBUCK;
    int t = threadIdx.x;
    int c0 = ch * CHUNK;
    int cend = min(c0 + CHUNK, E);
    hist[t] = 0;
    __syncthreads();
    for (int e = c0 + t; e < cend; e += 256)
        atomicAdd(&hist[((unsigned)ei[E + e]) >> 9], 1);
    __syncthreads();
    scn[t] = hist[t];
    __syncthreads();
    for (int off = 1; off < 256; off <<= 1) {
        int v = (t >= off) ? scn[t - off] : 0;
        __syncthreads();
        scn[t] += v;
        __syncthreads();
    }
    int excl = scn[t] - hist[t];
    lofs[t] = excl;
    lcur[t] = excl;
    if (hist[t] > 0) basex[t] = atomicAdd(&cur[t], hist[t]);   // bulk reservation
    __syncthreads();
    for (int e = c0 + t; e < cend; e += 256) {
        int dst = ei[E + e], src = ei[e];
        int b = ((unsigned)dst) >> 9;
        int r = atomicAdd(&lcur[b], 1);
        stage[r]  = (((unsigned)(dst & 511)) << 17) | (unsigned)src;
        stageB[r] = (unsigned char)b;
    }
    __syncthreads();
    int cnt = cend - c0;
    for (int i = t; i < cnt; i += 256) {
        int b = stageB[i];
        binned[basex[b] + (i - lofs[b])] = stage[i];   // contiguous run per bucket
    }
}

__global__ __launch_bounds__(256) void fine_kernel(int* __restrict__ cursor,
                                                   unsigned int* __restrict__ binned,
                                                   float* __restrict__ dinv, int2* __restrict__ rng) {
    __shared__ unsigned int stage[CAPE];          // 40KB
    __shared__ int hist[512], ofs[512], lcur[512];
    __shared__ int pscan[256];
    int bb = blockIdx.x;               // 0 .. 2*NBUCK-1
    int g = bb / NBUCK, bl = bb - g * NBUCK;
    int t = threadIdx.x;
    int gbase = bb * CAPE;             // absolute region base
    int cnt = min(cursor[bb] - gbase, CAPE);
    for (int i = t; i < cnt; i += 256) stage[i] = binned[gbase + i];
    hist[t] = 0; hist[t + 256] = 0;
    __syncthreads();
    for (int i = t; i < cnt; i += 256) atomicAdd(&hist[stage[i] >> 17], 1);
    __syncthreads();
    int a0 = hist[2 * t], a1 = hist[2 * t + 1];
    pscan[t] = a0 + a1;
    __syncthreads();
    for (int off = 1; off < 256; off <<= 1) {
        int v = (t >= off) ? pscan[t - off] : 0;
        __syncthreads();
        pscan[t] += v;
        __syncthreads();
    }
    int pex = pscan[t] - (a0 + a1);
    ofs[2 * t] = pex;       ofs[2 * t + 1] = pex + a0;
    lcur[2 * t] = pex;      lcur[2 * t + 1] = pex + a0;
    __syncthreads();
#pragma unroll
    for (int q = 0; q < 2; ++q) {
        int l = t + 256 * q;
        int node = bl * 512 + l;
        if (node < NN) {
            int dg = hist[l];
            dinv[(size_t)g * NN + node] = rsqrtf((float)(dg + 1));    // +1 self loop
            rng[(size_t)g * NN + node] = make_int2(gbase + ofs[l], gbase + ofs[l] + dg);
        }
    }
    for (int i = t; i < cnt; i += 256) {
        unsigned int p = stage[i];
        int l = p >> 17;
        int r = atomicAdd(&lcur[l], 1);
        binned[gbase + r] = p & 0x1FFFFu;      // in-place csr (src ids, graph-local)
    }
    if (t == 0) cursor[bb] = gbase;            // self-reset for next call
}

// ---------------- segment bounds ----------------

__global__ void bounds_kernel(const int* __restrict__ b0, const int* __restrict__ b1,
                              int* __restrict__ bounds, int n) {
    int t = threadIdx.x;            // 0..127
    int gb = t >> 6, j = t & 63;
    const int* b = gb ? b1 : b0;
    int lo = 0, hi = n;
    while (lo < hi) { int mid = (lo + hi) >> 1; if (b[mid] < j) lo = mid + 1; else hi = mid; }
    bounds[gb * 65 + j] = lo;
    if (j == 0) bounds[gb * 65 + 64] = n;
}

// ---------------- W pack: wp1 identity K-map (f32 A), wp2 permuted K-map (permuted bf16 A) ----------------

__global__ __launch_bounds__(256) void wpack_kernel(const float* __restrict__ W1, const float* __restrict__ W2,
                                                    unsigned short* __restrict__ Wp1, unsigned short* __restrict__ Wp2) {
    int o = blockIdx.x * 256 + threadIdx.x;      // 0 .. 32767
    bool second = o >= 16384;
    const float* W = second ? W2 : W1;
    unsigned short* Wp = second ? Wp2 : Wp1;
    int oo = o & 16383;
    int j = oo & 7, l = (oo >> 3) & 63, tile = oo >> 9;    // tile = kt*8+ct
    int kt = tile >> 3, ct = tile & 7;
    int kk = kt * 32 + ((l >> 4) << 3) + j;                // fragment K-slot
    int k = second ? PERM(kk) : kk;                        // storage-order K for layer 2
    int c = ct * 16 + (l & 15);
    Wp[oo] = f2bf(W[k * 128 + c]);
}

// permuted biases: pb[g][b] = bias_g[perm(b)]
__global__ void pbias_kernel(const float* __restrict__ b1, const float* __restrict__ b2, float* __restrict__ pb) {
    int t = threadIdx.x;
    int g = t >> 7, i = t & 127;
    pb[g * 128 + i] = (g ? b2 : b1)[PERM(i)];
}

// ---------------- MFMA GEMM layer1: both graphs, f32 A, permuted fp8 out ----------------

__global__ __launch_bounds__(256) void gemm_f32(const float* __restrict__ x0, const float* __restrict__ x1,
                                                const unsigned short* __restrict__ Wp,
                                                const float* __restrict__ dinv,
                                                uint2* __restrict__ Hs8, int nblk) {
    int g = blockIdx.x >= nblk;
    int bl = blockIdx.x - g * nblk;
    const float4* A = (const float4*)(g ? x1 : x0);
    int wave = threadIdx.x >> 6, lane = threadIdx.x & 63;
    int row_base = bl * 64 + wave * 16;
    int r = lane & 15, kg = lane >> 4;
    int rowc = min(row_base + r, NN - 1);

    bf16x8 af[4];
#pragma unroll
    for (int kt = 0; kt < 4; ++kt) {
        float4 p0 = A[(size_t)rowc * 32 + kt * 8 + kg * 2];
        float4 p1 = A[(size_t)rowc * 32 + kt * 8 + kg * 2 + 1];
        unsigned d0 = cvt_pk_bf16(p0.x, p0.y);
        unsigned d1 = cvt_pk_bf16(p0.z, p0.w);
        unsigned d2 = cvt_pk_bf16(p1.x, p1.y);
        unsigned d3 = cvt_pk_bf16(p1.z, p1.w);
        uint4 q = make_uint4(d0, d1, d2, d3);
        af[kt] = *(bf16x8*)&q;
    }

    f32x4 acc[8] = {};
    const bf16x8* Wf = (const bf16x8*)Wp;
#pragma unroll
    for (int kt = 0; kt < 4; ++kt) {
#pragma unroll
        for (int ct = 0; ct < 8; ++ct) {
            bf16x8 bf = Wf[(kt * 8 + ct) * 64 + lane];
            acc[ct] = __builtin_amdgcn_mfma_f32_16x16x32_bf16(af[kt], bf, acc[ct], 0, 0, 0);
        }
    }

    // epilogue: D row = row_base + kg*4 + reg, col = ct*16 + r -> storage bytes r*8+ct (contiguous 8B/lane)
#pragma unroll
    for (int reg = 0; reg < 4; ++reg) {
        int erow = row_base + (kg << 2) + reg;
        if (erow < NN) {
            float dv = dinv[(size_t)g * NN + erow];
            unsigned short p01 = fp8_pack2(acc[0][reg] * dv, acc[1][reg] * dv);
            unsigned short p23 = fp8_pack2(acc[2][reg] * dv, acc[3][reg] * dv);
            unsigned short p45 = fp8_pack2(acc[4][reg] * dv, acc[5][reg] * dv);
            unsigned short p67 = fp8_pack2(acc[6][reg] * dv, acc[7][reg] * dv);
            uint2 o;
            o.x = (unsigned)p01 | ((unsigned)p23 << 16);
            o.y = (unsigned)p45 | ((unsigned)p67 << 16);
            Hs8[(size_t)(g * NN + erow) * 16 + r] = o;
        }
    }
}

// ---------------- MFMA GEMM layer2: contiguous 2*NN rows, permuted bf16 A (wp2), permuted fp8 out ----------------

__global__ __launch_bounds__(256) void gemm_bf16(const uint4* __restrict__ A,
                                                 const unsigned short* __restrict__ Wp,
                                                 const float* __restrict__ dinv,
                                                 uint2* __restrict__ Hs8, int n2) {
    int wave = threadIdx.x >> 6, lane = threadIdx.x & 63;
    int row_base = blockIdx.x * 64 + wave * 16;
    int r = lane & 15, kg = lane >> 4;
    int rowc = min(row_base + r, n2 - 1);

    bf16x8 af[4];
#pragma unroll
    for (int kt = 0; kt < 4; ++kt) {
        uint4 p = A[(size_t)rowc * 16 + kt * 4 + kg];
        af[kt] = *(bf16x8*)&p;
    }

    f32x4 acc[8] = {};
    const bf16x8* Wf = (const bf16x8*)Wp;
#pragma unroll
    for (int kt = 0; kt < 4; ++kt) {
#pragma unroll
        for (int ct = 0; ct < 8; ++ct) {
            bf16x8 bf = Wf[(kt * 8 + ct) * 64 + lane];
            acc[ct] = __builtin_amdgcn_mfma_f32_16x16x32_bf16(af[kt], bf, acc[ct], 0, 0, 0);
        }
    }

#pragma unroll
    for (int reg = 0; reg < 4; ++reg) {
        int erow = row_base + (kg << 2) + reg;
        if (erow < n2) {
            float dv = dinv[erow];
            unsigned short p01 = fp8_pack2(acc[0][reg] * dv, acc[1][reg] * dv);
            unsigned short p23 = fp8_pack2(acc[2][reg] * dv, acc[3][reg] * dv);
            unsigned short p45 = fp8_pack2(acc[4][reg] * dv, acc[5][reg] * dv);
            unsigned short p67 = fp8_pack2(acc[6][reg] * dv, acc[7][reg] * dv);
            uint2 o;
            o.x = (unsigned)p01 | ((unsigned)p23 << 16);
            o.y = (unsigned)p45 | ((unsigned)p67 << 16);
            Hs8[(size_t)erow * 16 + r] = o;
        }
    }
}

// ---------------- conv gather: fp8 rows (128B), half-wave per edge, 16 rows in flight ----------------
// out16[d] = bf16( dinv[d] * ( sum_{s in N(d)} Hs[s] + Hs[d] ) + pbias )   (permuted byte order throughout)

__global__ __launch_bounds__(256) void conv_gather(const unsigned int* __restrict__ Hs8,
                                                   const int2* __restrict__ rng,
                                                   const int* __restrict__ csr, const float* __restrict__ dinv,
                                                   const float* __restrict__ pbias,
                                                   unsigned long long* __restrict__ out16, int n) {
    int wave = blockIdx.x * 4 + (threadIdx.x >> 6);
    int lane = threadIdx.x & 63;
    if (wave >= n) return;
    int d = wave;
    int half = lane >> 5;       // each half-wave gathers a different edge
    int h = lane & 31;          // dword index within 128B row: bytes 4h..4h+3
    int2 se = rng[d];
    int k0 = se.x, k1 = se.y;
    float a0 = 0.f, a1 = 0.f, a2 = 0.f, a3 = 0.f;
    int k = k0 + half;
    for (; k + 14 < k1; k += 16) {                   // 16 edges in flight per wave (8 per half)
        int s0 = __builtin_nontemporal_load(&csr[k]);
        int s1 = __builtin_nontemporal_load(&csr[k + 2]);
        int s2 = __builtin_nontemporal_load(&csr[k + 4]);
        int s3 = __builtin_nontemporal_load(&csr[k + 6]);
        int s4 = __builtin_nontemporal_load(&csr[k + 8]);
        int s5 = __builtin_nontemporal_load(&csr[k + 10]);
        int s6 = __builtin_nontemporal_load(&csr[k + 12]);
        int s7 = __builtin_nontemporal_load(&csr[k + 14]);
        unsigned u0 = Hs8[(size_t)s0 * 32 + h];
        unsigned u1 = Hs8[(size_t)s1 * 32 + h];
        unsigned u2 = Hs8[(size_t)s2 * 32 + h];
        unsigned u3 = Hs8[(size_t)s3 * 32 + h];
        unsigned u4 = Hs8[(size_t)s4 * 32 + h];
        unsigned u5 = Hs8[(size_t)s5 * 32 + h];
        unsigned u6 = Hs8[(size_t)s6 * 32 + h];
        unsigned u7 = Hs8[(size_t)s7 * 32 + h];
        fp8_acc4(u0, a0, a1, a2, a3);
        fp8_acc4(u1, a0, a1, a2, a3);
        fp8_acc4(u2, a0, a1, a2, a3);
        fp8_acc4(u3, a0, a1, a2, a3);
        fp8_acc4(u4, a0, a1, a2, a3);
        fp8_acc4(u5, a0, a1, a2, a3);
        fp8_acc4(u6, a0, a1, a2, a3);
        fp8_acc4(u7, a0, a1, a2, a3);
    }
    for (; k + 6 < k1; k += 8) {                     // 8 in flight
        int s0 = __builtin_nontemporal_load(&csr[k]);
        int s1 = __builtin_nontemporal_load(&csr[k + 2]);
        int s2 = __builtin_nontemporal_load(&csr[k + 4]);
        int s3 = __builtin_nontemporal_load(&csr[k + 6]);
        unsigned u0 = Hs8[(size_t)s0 * 32 + h];
        unsigned u1 = Hs8[(size_t)s1 * 32 + h];
        unsigned u2 = Hs8[(size_t)s2 * 32 + h];
        unsigned u3 = Hs8[(size_t)s3 * 32 + h];
        fp8_acc4(u0, a0, a1, a2, a3);
        fp8_acc4(u1, a0, a1, a2, a3);
        fp8_acc4(u2, a0, a1, a2, a3);
        fp8_acc4(u3, a0, a1, a2, a3);
    }
    for (; k < k1; k += 2) {
        unsigned u = Hs8[(size_t)__builtin_nontemporal_load(&csr[k]) * 32 + h];
        fp8_acc4(u, a0, a1, a2, a3);
    }
    if (half == 0) {            // self loop, added once
        unsigned ud = Hs8[(size_t)d * 32 + h];
        fp8_acc4(ud, a0, a1, a2, a3);
    }
    a0 += __shfl_xor(a0, 32);
    a1 += __shfl_xor(a1, 32);
    a2 += __shfl_xor(a2, 32);
    a3 += __shfl_xor(a3, 32);
    if (half == 0) {
        float dv = dinv[d];
        float4 b = ((const float4*)pbias)[h];
        unsigned lo = cvt_pk_bf16(fmaf(a0, dv, b.x), fmaf(a1, dv, b.y));
        unsigned hi = cvt_pk_bf16(fmaf(a2, dv, b.z), fmaf(a3, dv, b.w));
        unsigned long long o = (unsigned long long)lo | ((unsigned long long)hi << 32);
        __builtin_nontemporal_store(o, &out16[(size_t)d * 32 + h]);
    }
}

// ---------------- pooling stage 1: both graphs, partial sums over bf16 features ----------------

__global__ __launch_bounds__(256) void pool_part(const unsigned int* __restrict__ F16,
                                                 const int* __restrict__ bounds,
                                                 float* __restrict__ partial) {
    __shared__ float sh[512];
    int bid = blockIdx.x;                  // 0 .. 2*NG*PB-1
    int gb  = bid / (NG * PB);
    int rem = bid - gb * NG * PB;
    int gseg = rem / PB;
    int sub  = rem % PB;
    int s = bounds[gb * 65 + gseg], e = bounds[gb * 65 + gseg + 1];
    int len = e - s;
    int chunk = (len + PB - 1) / PB;
    int is = s + sub * chunk;
    int ie = min(is + chunk, e);
    int cp = threadIdx.x & 63;         // dword: slots 2cp, 2cp+1
    int quarter = threadIdx.x >> 6;    // node interleave 0..3
    size_t rbase = (size_t)gb * NN;
    float acc0 = 0.f, acc1 = 0.f;
    for (int i = is + quarter; i < ie; i += 4) {
        unsigned u = F16[(rbase + i) * 64 + cp];
        acc0 += __uint_as_float(u << 16);
        acc1 += __uint_as_float(u & 0xffff0000u);
    }
    sh[threadIdx.x] = acc0;
    sh[threadIdx.x + 256] = acc1;
    __syncthreads();
    if (threadIdx.x < 64) {
        float m0 = sh[cp] + sh[64 + cp] + sh[128 + cp] + sh[192 + cp];
        float m1 = sh[256 + cp] + sh[320 + cp] + sh[384 + cp] + sh[448 + cp];
        partial[((size_t)(gb * NG + gseg) * PB + sub) * 128 + 2 * cp]     = m0;
        partial[((size_t)(gb * NG + gseg) * PB + sub) * 128 + 2 * cp + 1] = m1;
    }
}

// ---------------- pooling stage 2 ----------------

__global__ __launch_bounds__(128) void pool_finish(const float* __restrict__ partial, const int* __restrict__ bounds,
                                                   float* __restrict__ pool) {
    int gg = blockIdx.x;              // 0..2*NG-1: gb*NG + g
    int gb = gg >> 6, g = gg & 63;
    int col = threadIdx.x;
    const float* p = partial + ((size_t)gb * NG + g) * PB * 128;
    float acc = 0.f;
#pragma unroll
    for (int sub = 0; sub < PB; ++sub) acc += p[sub * 128 + col];
    int len = bounds[gb * 65 + g + 1] - bounds[gb * 65 + g];
    pool[(size_t)gg * 128 + col] = acc / fmaxf((float)len, 1.0f);
}

// ---------------- classifier head (un-permutes feature order) ----------------

__global__ __launch_bounds__(128) void classifier_kernel(const float* __restrict__ pool,
                                                         const float* __restrict__ Wc1, const float* __restrict__ bc1,
                                                         const float* __restrict__ Wc2, const float* __restrict__ bc2,
                                                         float* __restrict__ out) {
    __shared__ float sh[128];
    int g = blockIdx.x;
    int j = threadIdx.x;
    float acc = bc1[j];
    const float* p0 = pool + (size_t)g * 128;          // graph-batch 0 mean (permuted slots)
    const float* p1 = pool + (size_t)(NG + g) * 128;   // graph-batch 1 mean
    for (int b = 0; b < 128; ++b) acc = fmaf(p0[b], Wc1[PERM(b) * 128 + j], acc);
    for (int b = 0; b < 128; ++b) acc = fmaf(p1[b], Wc1[(128 + PERM(b)) * 128 + j], acc);
    float h = 1.0f / (1.0f + expf(-acc));
    sh[j] = h * Wc2[j];
    __syncthreads();
    for (int off = 64; off > 0; off >>= 1) {
        if (j < off) sh[j] += sh[j + off];
        __syncthreads();
    }
    if (j == 0) out[g] = 1.0f / (1.0f + expf(-(sh[0] + bc2[0])));
}

// ---------------- launch ----------------

extern "C" void kernel_launch(void* const* d_in, const int* in_sizes, int n_in,
                              void* d_out, int out_size, void* d_ws, size_t ws_size,
                              hipStream_t stream) {
    const float* x[2]     = {(const float*)d_in[0], (const float*)d_in[1]};
    const int*   ei[2]    = {(const int*)d_in[2], (const int*)d_in[3]};
    const int*   batch[2] = {(const int*)d_in[4], (const int*)d_in[5]};
    const float* W1  = (const float*)d_in[6];
    const float* b1  = (const float*)d_in[7];
    const float* W2  = (const float*)d_in[8];
    const float* b2  = (const float*)d_in[9];
    const float* Wc1 = (const float*)d_in[10];
    const float* bc1 = (const float*)d_in[11];
    const float* Wc2 = (const float*)d_in[12];
    const float* bc2 = (const float*)d_in[13];
    float* out = (float*)d_out;

    char* w = (char*)d_ws;
    unsigned short*  buf16  = (unsigned short*)w;  w += (size_t)2 * NN * DHID * 2;     // bf16 features, both graphs
    unsigned char*   hs     = (unsigned char*)w;   w += (size_t)2 * NN * DHID;         // fp8 (1B/elem), both graphs
    unsigned int*    binned = (unsigned int*)w;    w += (size_t)2 * NBUCK * CAPE * 4;  // per-graph regions
    int2*            rng    = (int2*)w;            w += (size_t)2 * NN * 8;
    float*           dinv   = (float*)w;           w += (size_t)2 * NN * 4;
    unsigned short*  wp1    = (unsigned short*)w;  w += (size_t)128 * 128 * 2;
    unsigned short*  wp2    = (unsigned short*)w;  w += (size_t)128 * 128 * 2;
    float*           pb     = (float*)w;           w += 2 * 128 * 4;
    int*             cursor = (int*)w;             w += (size_t)2 * NBUCK * 4 + 16;
    int*             bounds = (int*)w;             w += 2 * 65 * 4 + 8;
    float*           partial= (float*)w;           w += (size_t)2 * NG * PB * DHID * 4;
    float*           pool   = (float*)w;           w += (size_t)2 * NG * DHID * 4;

    if ((size_t)(w - (char*)d_ws) > ws_size) return;  // workspace too small: fail loudly (no launch)

    const int nch = (NE + CHUNK - 1) / CHUNK;   // 196

    bounds_kernel<<<1, 128, 0, stream>>>(batch[0], batch[1], bounds, NN);
    wpack_kernel<<<128, 256, 0, stream>>>(W1, W2, wp1, wp2);
    pbias_kernel<<<1, 256, 0, stream>>>(b1, b2, pb);
    initcur_kernel<<<2, 256, 0, stream>>>(cursor);   // fine_kernel self-resets afterwards

    bin_kernel<<<2 * nch, 256, 0, stream>>>(ei[0], ei[1], cursor, binned, NE, nch);
    fine_kernel<<<2 * NBUCK, 256, 0, stream>>>(cursor, binned, dinv, rng);

    const int nblk = (NN + 63) / 64;        // 1563 per graph
    const int conv_grid = (NN + 3) / 4;

    // layer 1
    gemm_f32<<<2 * nblk, 256, 0, stream>>>(x[0], x[1], wp1, dinv, (uint2*)hs, nblk);
    for (int g = 0; g < 2; ++g)
        conv_gather<<<conv_grid, 256, 0, stream>>>((const unsigned int*)(hs + (size_t)g * NN * DHID),
                                                   rng + (size_t)g * NN, (const int*)binned,
                                                   dinv + (size_t)g * NN, pb,
                                                   (unsigned long long*)(buf16 + (size_t)g * NN * DHID), NN);
    // layer 2
    gemm_bf16<<<(2 * NN + 63) / 64, 256, 0, stream>>>((const uint4*)buf16, wp2, dinv, (uint2*)hs, 2 * NN);
    for (int g = 0; g < 2; ++g)
        conv_gather<<<conv_grid, 256, 0, stream>>>((const unsigned int*)(hs + (size_t)g * NN * DHID),
                                                   rng + (size_t)g * NN, (const int*)binned,
                                                   dinv + (size_t)g * NN, pb + 128,
                                                   (unsigned long long*)(buf16 + (size_t)g * NN * DHID), NN);

    pool_part<<<2 * NG * PB, 256, 0, stream>>>((const unsigned int*)buf16, bounds, partial);
    pool_finish<<<2 * NG, 128, 0, stream>>>(partial, bounds, pool);
    classifier_kernel<<<NG, 128, 0, stream>>>(pool, Wc1, bc1, Wc2, bc2, out);
}

// Round 14
// 365.254 us; speedup vs baseline: 1.1386x; 1.1386x over previous
//
#include <hip/hip_runtime.h>
#include <hip/hip_bf16.h>

#define NN 100000
#define NE 1600000
#define NG 64
#define DHID 128
#define PB 32       // blocks per graph segment in pooling stage 1
#define NBUCK 196   // dst buckets of 512 nodes (196*512 >= 100000)
#define CAPE 10240  // edge capacity per bucket (mean 8192, sigma ~90)
#define CHUNK 8192  // edges per binning workgroup

#if __has_builtin(__builtin_amdgcn_cvt_pk_f32_fp8) && __has_builtin(__builtin_amdgcn_cvt_pk_fp8_f32)
#define FP8_HW 1
#endif

typedef float f32x2 __attribute__((ext_vector_type(2)));
typedef float f32x4 __attribute__((ext_vector_type(4)));
typedef short bf16x8 __attribute__((ext_vector_type(8)));

// storage byte b <-> original column perm(b); perm(r*8+ct) = ct*16+r
#define PERM(b) ((((b) & 7) << 4) | ((b) >> 3))

// ---- fp8 e4m3fn software fallbacks (exact decode; RNE encode) ----
__device__ __forceinline__ float fp8_dec_sw(unsigned b) {
    unsigned u = ((b & 0x80u) << 24) | ((b & 0x7fu) << 20);
    return __uint_as_float(u) * 0x1p+120f;
}
__device__ __forceinline__ unsigned fp8_enc_sw(float f) {
    unsigned s = (__float_as_uint(f) >> 24) & 0x80u;
    float af = fabsf(f);
    if (!(af > 0x1p-10f)) return s;
    if (af > 448.f) af = 448.f;
    int e; float m = frexpf(af, &e);      // af = m*2^e, m in [0.5,1)
    int ee = e + 6;
    unsigned bits;
    if (ee <= 0) {
        int k = (int)rintf(af * 512.0f);
        if (k > 7) k = 7;
        bits = (unsigned)k;
    } else {
        int mm = (int)rintf(m * 16.0f);   // in [8,16]
        if (mm == 16) { mm = 8; ee += 1; }
        if (ee > 15) { ee = 15; mm = 14; }
        bits = ((unsigned)ee << 3) | (unsigned)(mm - 8);
    }
    return s | bits;
}

__device__ __forceinline__ unsigned short fp8_pack2(float a, float b) {
#ifdef FP8_HW
    return (unsigned short)__builtin_amdgcn_cvt_pk_fp8_f32(a, b, 0, false);
#else
    return (unsigned short)(fp8_enc_sw(a) | (fp8_enc_sw(b) << 8));
#endif
}

// accumulate 4 fp8 (one dword) into a0..a3
__device__ __forceinline__ void fp8_acc4(unsigned u, float& a0, float& a1, float& a2, float& a3) {
#ifdef FP8_HW
    f32x2 lo = __builtin_amdgcn_cvt_pk_f32_fp8((int)u, false);
    f32x2 hi = __builtin_amdgcn_cvt_pk_f32_fp8((int)u, true);
    a0 += lo[0]; a1 += lo[1]; a2 += hi[0]; a3 += hi[1];
#else
    a0 += fp8_dec_sw(u & 0xffu);
    a1 += fp8_dec_sw((u >> 8) & 0xffu);
    a2 += fp8_dec_sw((u >> 16) & 0xffu);
    a3 += fp8_dec_sw(u >> 24);
#endif
}

// f32 -> bf16 bits (RNE), scalar fallback path
__device__ __forceinline__ unsigned short f2bf(float f) {
    unsigned u = __float_as_uint(f);
    return (unsigned short)((u + 0x7FFFu + ((u >> 16) & 1u)) >> 16);
}

// packed f32x2 -> bf16x2 (low = a), single HW instruction on gfx950
__device__ __forceinline__ unsigned cvt_pk_bf16(float a, float b) {
#if defined(__AMDGCN__)
    unsigned r;
    asm("v_cvt_pk_bf16_f32 %0, %1, %2" : "=v"(r) : "v"(a), "v"(b));
    return r;
#else
    return (unsigned)f2bf(a) | ((unsigned)f2bf(b) << 16);
#endif
}

// ---------------- CSR build: two-level LDS-staged counting sort, both graphs ----------------

__global__ void initcur_kernel(int* __restrict__ cursor) {
    int i = blockIdx.x * 256 + threadIdx.x;
    if (i < 2 * NBUCK) cursor[i] = i * CAPE;
}

__global__ __launch_bounds__(256) void bin_kernel(const int* __restrict__ ei0, const int* __restrict__ ei1,
                                                  int* __restrict__ cursor,
                                                  unsigned int* __restrict__ binned, int E, int nch) {
    __shared__ int hist[256], scn[256], lofs[256], lcur[256], basex[256];
    __shared__ unsigned int stage[CHUNK];
    __shared__ unsigned char stageB[CHUNK];
    int g = blockIdx.x / nch;
    int ch = blockIdx.x - g * nch;
    const int* ei = g ? ei1 : ei0;
    int* cur = cursor + g * NBUCK;
    int t = threadIdx.x;
    int c0 = ch * CHUNK;
    int cend = min(c0 + CHUNK, E);
    hist[t] = 0;
    __syncthreads();
    for (int e = c0 + t; e < cend; e += 256)
        atomicAdd(&hist[((unsigned)ei[E + e]) >> 9], 1);
    __syncthreads();
    scn[t] = hist[t];
    __syncthreads();
    for (int off = 1; off < 256; off <<= 1) {
        int v = (t >= off) ? scn[t - off] : 0;
        __syncthreads();
        scn[t] += v;
        __syncthreads();
    }
    int excl = scn[t] - hist[t];
    lofs[t] = excl;
    lcur[t] = excl;
    if (hist[t] > 0) basex[t] = atomicAdd(&cur[t], hist[t]);   // bulk reservation
    __syncthreads();
    for (int e = c0 + t; e < cend; e += 256) {
        int dst = ei[E + e], src = ei[e];
        int b = ((unsigned)dst) >> 9;
        int r = atomicAdd(&lcur[b], 1);
        stage[r]  = (((unsigned)(dst & 511)) << 17) | (unsigned)src;
        stageB[r] = (unsigned char)b;
    }
    __syncthreads();
    int cnt = cend - c0;
    for (int i = t; i < cnt; i += 256) {
        int b = stageB[i];
        binned[basex[b] + (i - lofs[b])] = stage[i];   // contiguous run per bucket
    }
}

__global__ __launch_bounds__(256) void fine_kernel(int* __restrict__ cursor,
                                                   unsigned int* __restrict__ binned,
                                                   float* __restrict__ dinv, int2* __restrict__ rng) {
    __shared__ unsigned int stage[CAPE];          // 40KB
    __shared__ int hist[512], ofs[512], lcur[512];
    __shared__ int pscan[256];
    int bb = blockIdx.x;               // 0 .. 2*NBUCK-1
    int g = bb / NBUCK, bl = bb - g * NBUCK;
    int t = threadIdx.x;
    int gbase = bb * CAPE;             // absolute region base
    int cnt = min(cursor[bb] - gbase, CAPE);
    for (int i = t; i < cnt; i += 256) stage[i] = binned[gbase + i];
    hist[t] = 0; hist[t + 256] = 0;
    __syncthreads();
    for (int i = t; i < cnt; i += 256) atomicAdd(&hist[stage[i] >> 17], 1);
    __syncthreads();
    int a0 = hist[2 * t], a1 = hist[2 * t + 1];
    pscan[t] = a0 + a1;
    __syncthreads();
    for (int off = 1; off < 256; off <<= 1) {
        int v = (t >= off) ? pscan[t - off] : 0;
        __syncthreads();
        pscan[t] += v;
        __syncthreads();
    }
    int pex = pscan[t] - (a0 + a1);
    ofs[2 * t] = pex;       ofs[2 * t + 1] = pex + a0;
    lcur[2 * t] = pex;      lcur[2 * t + 1] = pex + a0;
    __syncthreads();
#pragma unroll
    for (int q = 0; q < 2; ++q) {
        int l = t + 256 * q;
        int node = bl * 512 + l;
        if (node < NN) {
            int dg = hist[l];
            dinv[(size_t)g * NN + node] = rsqrtf((float)(dg + 1));    // +1 self loop
            rng[(size_t)g * NN + node] = make_int2(gbase + ofs[l], gbase + ofs[l] + dg);
        }
    }
    for (int i = t; i < cnt; i += 256) {
        unsigned int p = stage[i];
        int l = p >> 17;
        int r = atomicAdd(&lcur[l], 1);
        binned[gbase + r] = p & 0x1FFFFu;      // in-place csr (src ids, graph-local)
    }
    if (t == 0) cursor[bb] = gbase;            // self-reset for next call
}

// ---------------- segment bounds ----------------

__global__ void bounds_kernel(const int* __restrict__ b0, const int* __restrict__ b1,
                              int* __restrict__ bounds, int n) {
    int t = threadIdx.x;            // 0..127
    int gb = t >> 6, j = t & 63;
    const int* b = gb ? b1 : b0;
    int lo = 0, hi = n;
    while (lo < hi) { int mid = (lo + hi) >> 1; if (b[mid] < j) lo = mid + 1; else hi = mid; }
    bounds[gb * 65 + j] = lo;
    if (j == 0) bounds[gb * 65 + 64] = n;
}

// ---------------- W pack: wp1 identity K-map (f32 A), wp2 permuted K-map (permuted bf16 A) ----------------

__global__ __launch_bounds__(256) void wpack_kernel(const float* __restrict__ W1, const float* __restrict__ W2,
                                                    unsigned short* __restrict__ Wp1, unsigned short* __restrict__ Wp2) {
    int o = blockIdx.x * 256 + threadIdx.x;      // 0 .. 32767
    bool second = o >= 16384;
    const float* W = second ? W2 : W1;
    unsigned short* Wp = second ? Wp2 : Wp1;
    int oo = o & 16383;
    int j = oo & 7, l = (oo >> 3) & 63, tile = oo >> 9;    // tile = kt*8+ct
    int kt = tile >> 3, ct = tile & 7;
    int kk = kt * 32 + ((l >> 4) << 3) + j;                // fragment K-slot
    int k = second ? PERM(kk) : kk;                        // storage-order K for layer 2
    int c = ct * 16 + (l & 15);
    Wp[oo] = f2bf(W[k * 128 + c]);
}

// permuted biases: pb[g][b] = bias_g[perm(b)]
__global__ void pbias_kernel(const float* __restrict__ b1, const float* __restrict__ b2, float* __restrict__ pb) {
    int t = threadIdx.x;
    int g = t >> 7, i = t & 127;
    pb[g * 128 + i] = (g ? b2 : b1)[PERM(i)];
}

// ---------------- MFMA GEMM layer1: both graphs, f32 A, permuted fp8 out ----------------

__global__ __launch_bounds__(256) void gemm_f32(const float* __restrict__ x0, const float* __restrict__ x1,
                                                const unsigned short* __restrict__ Wp,
                                                const float* __restrict__ dinv,
                                                uint2* __restrict__ Hs8, int nblk) {
    int g = blockIdx.x >= nblk;
    int bl = blockIdx.x - g * nblk;
    const float4* A = (const float4*)(g ? x1 : x0);
    int wave = threadIdx.x >> 6, lane = threadIdx.x & 63;
    int row_base = bl * 64 + wave * 16;
    int r = lane & 15, kg = lane >> 4;
    int rowc = min(row_base + r, NN - 1);

    bf16x8 af[4];
#pragma unroll
    for (int kt = 0; kt < 4; ++kt) {
        float4 p0 = A[(size_t)rowc * 32 + kt * 8 + kg * 2];
        float4 p1 = A[(size_t)rowc * 32 + kt * 8 + kg * 2 + 1];
        unsigned d0 = cvt_pk_bf16(p0.x, p0.y);
        unsigned d1 = cvt_pk_bf16(p0.z, p0.w);
        unsigned d2 = cvt_pk_bf16(p1.x, p1.y);
        unsigned d3 = cvt_pk_bf16(p1.z, p1.w);
        uint4 q = make_uint4(d0, d1, d2, d3);
        af[kt] = *(bf16x8*)&q;
    }

    f32x4 acc[8] = {};
    const bf16x8* Wf = (const bf16x8*)Wp;
#pragma unroll
    for (int kt = 0; kt < 4; ++kt) {
#pragma unroll
        for (int ct = 0; ct < 8; ++ct) {
            bf16x8 bf = Wf[(kt * 8 + ct) * 64 + lane];
            acc[ct] = __builtin_amdgcn_mfma_f32_16x16x32_bf16(af[kt], bf, acc[ct], 0, 0, 0);
        }
    }

    // epilogue: D row = row_base + kg*4 + reg, col = ct*16 + r -> storage bytes r*8+ct (contiguous 8B/lane)
#pragma unroll
    for (int reg = 0; reg < 4; ++reg) {
        int erow = row_base + (kg << 2) + reg;
        if (erow < NN) {
            float dv = dinv[(size_t)g * NN + erow];
            unsigned short p01 = fp8_pack2(acc[0][reg] * dv, acc[1][reg] * dv);
            unsigned short p23 = fp8_pack2(acc[2][reg] * dv, acc[3][reg] * dv);
            unsigned short p45 = fp8_pack2(acc[4][reg] * dv, acc[5][reg] * dv);
            unsigned short p67 = fp8_pack2(acc[6][reg] * dv, acc[7][reg] * dv);
            uint2 o;
            o.x = (unsigned)p01 | ((unsigned)p23 << 16);
            o.y = (unsigned)p45 | ((unsigned)p67 << 16);
            Hs8[(size_t)(g * NN + erow) * 16 + r] = o;
        }
    }
}

// ---------------- MFMA GEMM layer2: contiguous 2*NN rows, permuted bf16 A (wp2), permuted fp8 out ----------------

__global__ __launch_bounds__(256) void gemm_bf16(const uint4* __restrict__ A,
                                                 const unsigned short* __restrict__ Wp,
                                                 const float* __restrict__ dinv,
                                                 uint2* __restrict__ Hs8, int n2) {
    int wave = threadIdx.x >> 6, lane = threadIdx.x & 63;
    int row_base = blockIdx.x * 64 + wave * 16;
    int r = lane & 15, kg = lane >> 4;
    int rowc = min(row_base + r, n2 - 1);

    bf16x8 af[4];
#pragma unroll
    for (int kt = 0; kt < 4; ++kt) {
        uint4 p = A[(size_t)rowc * 16 + kt * 4 + kg];
        af[kt] = *(bf16x8*)&p;
    }

    f32x4 acc[8] = {};
    const bf16x8* Wf = (const bf16x8*)Wp;
#pragma unroll
    for (int kt = 0; kt < 4; ++kt) {
#pragma unroll
        for (int ct = 0; ct < 8; ++ct) {
            bf16x8 bf = Wf[(kt * 8 + ct) * 64 + lane];
            acc[ct] = __builtin_amdgcn_mfma_f32_16x16x32_bf16(af[kt], bf, acc[ct], 0, 0, 0);
        }
    }

#pragma unroll
    for (int reg = 0; reg < 4; ++reg) {
        int erow = row_base + (kg << 2) + reg;
        if (erow < n2) {
            float dv = dinv[erow];
            unsigned short p01 = fp8_pack2(acc[0][reg] * dv, acc[1][reg] * dv);
            unsigned short p23 = fp8_pack2(acc[2][reg] * dv, acc[3][reg] * dv);
            unsigned short p45 = fp8_pack2(acc[4][reg] * dv, acc[5][reg] * dv);
            unsigned short p67 = fp8_pack2(acc[6][reg] * dv, acc[7][reg] * dv);
            uint2 o;
            o.x = (unsigned)p01 | ((unsigned)p23 << 16);
            o.y = (unsigned)p45 | ((unsigned)p67 << 16);
            Hs8[(size_t)erow * 16 + r] = o;
        }
    }
}

// ---------------- conv gather: fp8 rows (128B), half-wave per edge, 16 rows in flight ----------------
// out16[d] = bf16( dinv[d] * ( sum_{s in N(d)} Hs[s] + Hs[d] ) + pbias )   (permuted byte order throughout)

__global__ __launch_bounds__(256) void conv_gather(const unsigned int* __restrict__ Hs8,
                                                   const int2* __restrict__ rng,
                                                   const int* __restrict__ csr, const float* __restrict__ dinv,
                                                   const float* __restrict__ pbias,
                                                   unsigned long long* __restrict__ out16, int n) {
    int wave = blockIdx.x * 4 + (threadIdx.x >> 6);
    int lane = threadIdx.x & 63;
    if (wave >= n) return;
    int d = wave;
    int half = lane >> 5;       // each half-wave gathers a different edge
    int h = lane & 31;          // dword index within 128B row: bytes 4h..4h+3
    int2 se = rng[d];
    int k0 = se.x, k1 = se.y;
    float a0 = 0.f, a1 = 0.f, a2 = 0.f, a3 = 0.f;
    int k = k0 + half;
    for (; k + 14 < k1; k += 16) {                   // 16 edges in flight per wave (8 per half)
        int s0 = csr[k],      s1 = csr[k + 2],  s2 = csr[k + 4],  s3 = csr[k + 6];
        int s4 = csr[k + 8],  s5 = csr[k + 10], s6 = csr[k + 12], s7 = csr[k + 14];
        unsigned u0 = Hs8[(size_t)s0 * 32 + h];
        unsigned u1 = Hs8[(size_t)s1 * 32 + h];
        unsigned u2 = Hs8[(size_t)s2 * 32 + h];
        unsigned u3 = Hs8[(size_t)s3 * 32 + h];
        unsigned u4 = Hs8[(size_t)s4 * 32 + h];
        unsigned u5 = Hs8[(size_t)s5 * 32 + h];
        unsigned u6 = Hs8[(size_t)s6 * 32 + h];
        unsigned u7 = Hs8[(size_t)s7 * 32 + h];
        fp8_acc4(u0, a0, a1, a2, a3);
        fp8_acc4(u1, a0, a1, a2, a3);
        fp8_acc4(u2, a0, a1, a2, a3);
        fp8_acc4(u3, a0, a1, a2, a3);
        fp8_acc4(u4, a0, a1, a2, a3);
        fp8_acc4(u5, a0, a1, a2, a3);
        fp8_acc4(u6, a0, a1, a2, a3);
        fp8_acc4(u7, a0, a1, a2, a3);
    }
    for (; k + 6 < k1; k += 8) {                     // 8 in flight
        int s0 = csr[k], s1 = csr[k + 2], s2 = csr[k + 4], s3 = csr[k + 6];
        unsigned u0 = Hs8[(size_t)s0 * 32 + h];
        unsigned u1 = Hs8[(size_t)s1 * 32 + h];
        unsigned u2 = Hs8[(size_t)s2 * 32 + h];
        unsigned u3 = Hs8[(size_t)s3 * 32 + h];
        fp8_acc4(u0, a0, a1, a2, a3);
        fp8_acc4(u1, a0, a1, a2, a3);
        fp8_acc4(u2, a0, a1, a2, a3);
        fp8_acc4(u3, a0, a1, a2, a3);
    }
    for (; k < k1; k += 2) {
        unsigned u = Hs8[(size_t)csr[k] * 32 + h];
        fp8_acc4(u, a0, a1, a2, a3);
    }
    if (half == 0) {            // self loop, added once
        unsigned ud = Hs8[(size_t)d * 32 + h];
        fp8_acc4(ud, a0, a1, a2, a3);
    }
    a0 += __shfl_xor(a0, 32);
    a1 += __shfl_xor(a1, 32);
    a2 += __shfl_xor(a2, 32);
    a3 += __shfl_xor(a3, 32);
    if (half == 0) {
        float dv = dinv[d];
        float4 b = ((const float4*)pbias)[h];
        unsigned lo = cvt_pk_bf16(fmaf(a0, dv, b.x), fmaf(a1, dv, b.y));
        unsigned hi = cvt_pk_bf16(fmaf(a2, dv, b.z), fmaf(a3, dv, b.w));
        unsigned long long o = (unsigned long long)lo | ((unsigned long long)hi << 32);
        out16[(size_t)d * 32 + h] = o;
    }
}

// ---------------- pooling stage 1: both graphs, partial sums over bf16 features ----------------

__global__ __launch_bounds__(256) void pool_part(const unsigned int* __restrict__ F16,
                                                 const int* __restrict__ bounds,
                                                 float* __restrict__ partial) {
    __shared__ float sh[512];
    int bid = blockIdx.x;                  // 0 .. 2*NG*PB-1
    int gb  = bid / (NG * PB);
    int rem = bid - gb * NG * PB;
    int gseg = rem / PB;
    int sub  = rem % PB;
    int s = bounds[gb * 65 + gseg], e = bounds[gb * 65 + gseg + 1];
    int len = e - s;
    int chunk = (len + PB - 1) / PB;
    int is = s + sub * chunk;
    int ie = min(is + chunk, e);
    int cp = threadIdx.x & 63;         // dword: slots 2cp, 2cp+1
    int quarter = threadIdx.x >> 6;    // node interleave 0..3
    size_t rbase = (size_t)gb * NN;
    float acc0 = 0.f, acc1 = 0.f;
    for (int i = is + quarter; i < ie; i += 4) {
        unsigned u = F16[(rbase + i) * 64 + cp];
        acc0 += __uint_as_float(u << 16);
        acc1 += __uint_as_float(u & 0xffff0000u);
    }
    sh[threadIdx.x] = acc0;
    sh[threadIdx.x + 256] = acc1;
    __syncthreads();
    if (threadIdx.x < 64) {
        float m0 = sh[cp] + sh[64 + cp] + sh[128 + cp] + sh[192 + cp];
        float m1 = sh[256 + cp] + sh[320 + cp] + sh[384 + cp] + sh[448 + cp];
        partial[((size_t)(gb * NG + gseg) * PB + sub) * 128 + 2 * cp]     = m0;
        partial[((size_t)(gb * NG + gseg) * PB + sub) * 128 + 2 * cp + 1] = m1;
    }
}

// ---------------- pooling stage 2 ----------------

__global__ __launch_bounds__(128) void pool_finish(const float* __restrict__ partial, const int* __restrict__ bounds,
                                                   float* __restrict__ pool) {
    int gg = blockIdx.x;              // 0..2*NG-1: gb*NG + g
    int gb = gg >> 6, g = gg & 63;
    int col = threadIdx.x;
    const float* p = partial + ((size_t)gb * NG + g) * PB * 128;
    float acc = 0.f;
#pragma unroll
    for (int sub = 0; sub < PB; ++sub) acc += p[sub * 128 + col];
    int len = bounds[gb * 65 + g + 1] - bounds[gb * 65 + g];
    pool[(size_t)gg * 128 + col] = acc / fmaxf((float)len, 1.0f);
}

// ---------------- classifier head (un-permutes feature order) ----------------

__global__ __launch_bounds__(128) void classifier_kernel(const float* __restrict__ pool,
                                                         const float* __restrict__ Wc1, const float* __restrict__ bc1,
                                                         const float* __restrict__ Wc2, const float* __restrict__ bc2,
                                                         float* __restrict__ out) {
    __shared__ float sh[128];
    int g = blockIdx.x;
    int j = threadIdx.x;
    float acc = bc1[j];
    const float* p0 = pool + (size_t)g * 128;          // graph-batch 0 mean (permuted slots)
    const float* p1 = pool + (size_t)(NG + g) * 128;   // graph-batch 1 mean
    for (int b = 0; b < 128; ++b) acc = fmaf(p0[b], Wc1[PERM(b) * 128 + j], acc);
    for (int b = 0; b < 128; ++b) acc = fmaf(p1[b], Wc1[(128 + PERM(b)) * 128 + j], acc);
    float h = 1.0f / (1.0f + expf(-acc));
    sh[j] = h * Wc2[j];
    __syncthreads();
    for (int off = 64; off > 0; off >>= 1) {
        if (j < off) sh[j] += sh[j + off];
        __syncthreads();
    }
    if (j == 0) out[g] = 1.0f / (1.0f + expf(-(sh[0] + bc2[0])));
}

// ---------------- launch ----------------

extern "C" void kernel_launch(void* const* d_in, const int* in_sizes, int n_in,
                              void* d_out, int out_size, void* d_ws, size_t ws_size,
                              hipStream_t stream) {
    const float* x[2]     = {(const float*)d_in[0], (const float*)d_in[1]};
    const int*   ei[2]    = {(const int*)d_in[2], (const int*)d_in[3]};
    const int*   batch[2] = {(const int*)d_in[4], (const int*)d_in[5]};
    const float* W1  = (const float*)d_in[6];
    const float* b1  = (const float*)d_in[7];
    const float* W2  = (const float*)d_in[8];
    const float* b2  = (const float*)d_in[9];
    const float* Wc1 = (const float*)d_in[10];
    const float* bc1 = (const float*)d_in[11];
    const float* Wc2 = (const float*)d_in[12];
    const float* bc2 = (const float*)d_in[13];
    float* out = (float*)d_out;

    char* w = (char*)d_ws;
    unsigned short*  buf16  = (unsigned short*)w;  w += (size_t)2 * NN * DHID * 2;     // bf16 features, both graphs
    unsigned char*   hs     = (unsigned char*)w;   w += (size_t)2 * NN * DHID;         // fp8 (1B/elem), both graphs
    unsigned int*    binned = (unsigned int*)w;    w += (size_t)2 * NBUCK * CAPE * 4;  // per-graph regions
    int2*            rng    = (int2*)w;            w += (size_t)2 * NN * 8;
    float*           dinv   = (float*)w;           w += (size_t)2 * NN * 4;
    unsigned short*  wp1    = (unsigned short*)w;  w += (size_t)128 * 128 * 2;
    unsigned short*  wp2    = (unsigned short*)w;  w += (size_t)128 * 128 * 2;
    float*           pb     = (float*)w;           w += 2 * 128 * 4;
    int*             cursor = (int*)w;             w += (size_t)2 * NBUCK * 4 + 16;
    int*             bounds = (int*)w;             w += 2 * 65 * 4 + 8;
    float*           partial= (float*)w;           w += (size_t)2 * NG * PB * DHID * 4;
    float*           pool   = (float*)w;           w += (size_t)2 * NG * DHID * 4;

    if ((size_t)(w - (char*)d_ws) > ws_size) return;  // workspace too small: fail loudly (no launch)

    const int nch = (NE + CHUNK - 1) / CHUNK;   // 196

    bounds_kernel<<<1, 128, 0, stream>>>(batch[0], batch[1], bounds, NN);
    wpack_kernel<<<128, 256, 0, stream>>>(W1, W2, wp1, wp2);
    pbias_kernel<<<1, 256, 0, stream>>>(b1, b2, pb);
    initcur_kernel<<<2, 256, 0, stream>>>(cursor);   // fine_kernel self-resets afterwards

    bin_kernel<<<2 * nch, 256, 0, stream>>>(ei[0], ei[1], cursor, binned, NE, nch);
    fine_kernel<<<2 * NBUCK, 256, 0, stream>>>(cursor, binned, dinv, rng);

    const int nblk = (NN + 63) / 64;        // 1563 per graph
    const int conv_grid = (NN + 3) / 4;

    // layer 1
    gemm_f32<<<2 * nblk, 256, 0, stream>>>(x[0], x[1], wp1, dinv, (uint2*)hs, nblk);
    for (int g = 0; g < 2; ++g)
        conv_gather<<<conv_grid, 256, 0, stream>>>((const unsigned int*)(hs + (size_t)g * NN * DHID),
                                                   rng + (size_t)g * NN, (const int*)binned,
                                                   dinv + (size_t)g * NN, pb,
                                                   (unsigned long long*)(buf16 + (size_t)g * NN * DHID), NN);
    // layer 2
    gemm_bf16<<<(2 * NN + 63) / 64, 256, 0, stream>>>((const uint4*)buf16, wp2, dinv, (uint2*)hs, 2 * NN);
    for (int g = 0; g < 2; ++g)
        conv_gather<<<conv_grid, 256, 0, stream>>>((const unsigned int*)(hs + (size_t)g * NN * DHID),
                                                   rng + (size_t)g * NN, (const int*)binned,
                                                   dinv + (size_t)g * NN, pb + 128,
                                                   (unsigned long long*)(buf16 + (size_t)g * NN * DHID), NN);

    pool_part<<<2 * NG * PB, 256, 0, stream>>>((const unsigned int*)buf16, bounds, partial);
    pool_finish<<<2 * NG, 128, 0, stream>>>(partial, bounds, pool);
    classifier_kernel<<<NG, 128, 0, stream>>>(pool, Wc1, bc1, Wc2, bc2, out);
}